// Round 2
// baseline (539.905 us; speedup 1.0000x reference)
//
#include <hip/hip_runtime.h>
#include <stdint.h>

// h1[b,o] = sum_{i,j,k} t_i a_j v_k W1[o, i*97*97 + j*97 + k], t/a/v = [1, x].
// Block blk = o*97+i owns contiguous W span [blk*9409, +9409).
// Inner k (k=1..96) = K=96 bf16 MFMA GEMM vs video; k=0/j=0/i=0 are biases.
//
// R2: W converted fp32->bf16 ONCE at staging into padded LDS rows
// ([97][104] bf16, 208 B stride -> every A-frag is one aligned ds_read_b128);
// bias column (k=0) kept fp32 in a separate LDS array. Kills the R1
// bottleneck (8x ds_read_b32 + 8x f2bf per fragment in the hot loop).

#define HID    96
#define NP1    97
#define ROWLEN 9409      // 97*97 floats per (o,i) tile
#define NBLK   9312      // 96*97 blocks
#define BATCH  64
#define RSTR   104       // bf16 LDS row stride: 96 payload + 8 pad (208 B, 16B-aligned)

typedef short bf16x8 __attribute__((ext_vector_type(8)));
typedef float f32x4  __attribute__((ext_vector_type(4)));

__device__ __forceinline__ uint32_t pack2bf(float lo, float hi) {
    union { float f; uint32_t u; } a, b; a.f = lo; b.f = hi;
    uint32_t ra = (a.u + 0x7fffu + ((a.u >> 16) & 1u)) >> 16;          // RNE, low half
    uint32_t rb = (b.u + 0x7fffu + ((b.u >> 16) & 1u)) & 0xffff0000u;  // RNE, high half
    return ra | rb;
}

__global__ __launch_bounds__(256, 6)
void fusion_gemm(const float* __restrict__ W1,
                 const float* __restrict__ text_x,
                 const float* __restrict__ audio_x,
                 const float* __restrict__ video_x,
                 float* __restrict__ h1pre)   // [96][64] accumulator (pre-zeroed)
{
    __shared__ __align__(16) short Wbf[NP1 * RSTR];   // [j][k-1] bf16, 20.2 KB
    __shared__ float biasF[NP1];                      // W[j][0] fp32

    const int tid = threadIdx.x;
    const int blk = blockIdx.x;          // = o*97 + i
    const int o = blk / 97;
    const int i = blk - o * 97;
    const float* Wt = W1 + (long)blk * ROWLEN;

    // ---- bias column k=0 (lines shared with row loads -> L2 hits) ----
    for (int j = tid; j < NP1; j += 256) biasF[j] = Wt[j * NP1];

    // ---- stage k=1..96 as bf16: item w = (row j, 8-wide segment s) ----
    for (int w = tid; w < NP1 * 12; w += 256) {
        int j = w / 12;
        int s = w - j * 12;
        const float* p = Wt + j * NP1 + 1 + s * 8;   // contiguous across lanes
        uint4 q;
        q.x = pack2bf(p[0], p[1]);
        q.y = pack2bf(p[2], p[3]);
        q.z = pack2bf(p[4], p[5]);
        q.w = pack2bf(p[6], p[7]);
        // byte addr = 208*j + 16*s  -> 16B aligned
        *reinterpret_cast<uint4*>(&Wbf[j * RSTR + s * 8]) = q;
    }

    const int lane = tid & 63;
    const int wave = tid >> 6;
    const int quad = lane >> 4;
    const int col  = lane & 15;
    const int b    = wave * 16 + col;    // this wave's batch element per lane

    // ---- B fragments: video[b][k], K=96 = 3 k-steps of 32 ----
    // B-frag layout: lane holds B[k = quad*8+e][n = lane&15]
    bf16x8 bfrag[3];
#pragma unroll
    for (int ks = 0; ks < 3; ++ks) {
        const float* vp = video_x + b * HID + ks * 32 + quad * 8;
        union { bf16x8 v; uint32_t d[4]; } u;
        u.d[0] = pack2bf(vp[0], vp[1]);
        u.d[1] = pack2bf(vp[2], vp[3]);
        u.d[2] = pack2bf(vp[4], vp[5]);
        u.d[3] = pack2bf(vp[6], vp[7]);
        bfrag[ks] = u.v;
    }

    __syncthreads();

    // ---- MFMA: U[j,b] = sum_k W[j,1+k]*video[b,k]; 7 m-tiles of 16 j ----
    f32x4 acc[7];
#pragma unroll
    for (int mt = 0; mt < 7; ++mt) acc[mt] = (f32x4){0.f, 0.f, 0.f, 0.f};

#pragma unroll
    for (int ks = 0; ks < 3; ++ks) {
#pragma unroll
        for (int mt = 0; mt < 7; ++mt) {
            int j  = mt * 16 + col;               // A-frag row m
            int je = j > 96 ? 96 : j;             // clamp; garbage rows unused
            // byte addr = 208*je + 64*ks + 16*quad -> one aligned ds_read_b128
            bf16x8 af = *reinterpret_cast<const bf16x8*>(&Wbf[je * RSTR + ks * 32 + quad * 8]);
            acc[mt] = __builtin_amdgcn_mfma_f32_16x16x32_bf16(af, bfrag[ks], acc[mt], 0, 0, 0);
        }
    }

    // ---- epilogue: S[b] = sum_j a[b,j] * (U[j,b] + W[j,0]) ----
    // D layout: col = lane&15 -> b, row = quad*4 + reg -> j  (verified R1)
    float s = 0.f;
#pragma unroll
    for (int mt = 0; mt < 7; ++mt) {
#pragma unroll
        for (int r = 0; r < 4; ++r) {
            int j = mt * 16 + quad * 4 + r;
            if (j < 97) {
                float u  = acc[mt][r] + biasF[j];                    // + k=0 bias
                float aw = (j == 0) ? 1.f : audio_x[b * HID + (j - 1)];
                s += u * aw;
            }
        }
    }
    s += __shfl_xor(s, 16);
    s += __shfl_xor(s, 32);   // all quads hold full sum over j

    if (quad == 0) {
        float tw = (i == 0) ? 1.f : text_x[b * HID + (i - 1)];
        atomicAdd(&h1pre[o * BATCH + b], s * tw);
    }
}

__global__ __launch_bounds__(64)
void mlp_tail(const float* __restrict__ h1pre, const float* __restrict__ b1,
              const float* __restrict__ W2, const float* __restrict__ b2,
              const float* __restrict__ W3, const float* __restrict__ b3,
              float* __restrict__ out)
{
    __shared__ float h1s[96];
    __shared__ float h2s[48];
    const int b = blockIdx.x;
    const int t = threadIdx.x;
    for (int o = t; o < 96; o += 64) {
        float v = h1pre[o * BATCH + b] + b1[o];
        h1s[o] = v > 0.f ? v : 0.f;
    }
    __syncthreads();
    if (t < 48) {
        float acc = b2[t];
#pragma unroll 8
        for (int o = 0; o < 96; ++o) acc += W2[t * 96 + o] * h1s[o];
        h2s[t] = acc > 0.f ? acc : 0.f;
    }
    __syncthreads();
    if (t < 3) {
        float acc = b3[t];
#pragma unroll
        for (int c = 0; c < 48; ++c) acc += W3[t * 48 + c] * h2s[c];
        out[b * 3 + t] = acc;
    }
}

extern "C" void kernel_launch(void* const* d_in, const int* in_sizes, int n_in,
                              void* d_out, int out_size, void* d_ws, size_t ws_size,
                              hipStream_t stream)
{
    const float* text  = (const float*)d_in[0];
    const float* audio = (const float*)d_in[1];
    const float* video = (const float*)d_in[2];
    const float* W1    = (const float*)d_in[3];
    const float* b1    = (const float*)d_in[4];
    const float* W2    = (const float*)d_in[5];
    const float* b2    = (const float*)d_in[6];
    const float* W3    = (const float*)d_in[7];
    const float* b3    = (const float*)d_in[8];
    float* h1pre = (float*)d_ws;                       // 96*64 fp32 = 24.6 KB

    hipMemsetAsync(h1pre, 0, HID * BATCH * sizeof(float), stream);
    fusion_gemm<<<NBLK, 256, 0, stream>>>(W1, text, audio, video, h1pre);
    mlp_tail<<<BATCH, 64, 0, stream>>>(h1pre, b1, W2, b2, W3, b3, (float*)d_out);
}

// Round 3
// 491.856 us; speedup vs baseline: 1.0977x; 1.0977x over previous
//
#include <hip/hip_runtime.h>
#include <stdint.h>

// h1[b,o] = sum_{i,j,k} t_i a_j v_k W1[o, i*97*97 + j*97 + k], t/a/v = [1, x].
// Tile (o,i) = contiguous 9409-float W span. Inner k (k=1..96) = K=96 bf16
// MFMA GEMM vs video; k=0 / j=0 / i=0 are the prepended-ones bias terms.
//
// R3: persistent chunked blocks. Grid = 96 o x 8 i-chunks = 768 blocks
// (= 3/CU at 41 KB LDS). Each block streams its 12-13 W tiles through a
// double-buffered LDS (one barrier per tile, stage n+1 overlaps compute n),
// folds the i-dimension (x t_i) IN REGISTER, and issues one atomicAdd per
// (o,b) per chunk (49K atomics total vs R2's 596K storm on 6K addresses).
// Video B-fragments + 28 audio epilogue weights hoisted out of the loop.

#define HID    96
#define NP1    97
#define ROWLEN 9409      // 97*97 floats per (o,i) tile
#define BATCH  64
#define RSTR   104       // bf16 LDS row stride: 96 payload + 8 pad (16B-aligned rows)

typedef short bf16x8 __attribute__((ext_vector_type(8)));
typedef float f32x4  __attribute__((ext_vector_type(4)));

__device__ __forceinline__ uint32_t pack2bf(float lo, float hi) {
    union { float f; uint32_t u; } a, b; a.f = lo; b.f = hi;
    uint32_t ra = (a.u + 0x7fffu + ((a.u >> 16) & 1u)) >> 16;          // RNE lo
    uint32_t rb = (b.u + 0x7fffu + ((b.u >> 16) & 1u)) & 0xffff0000u;  // RNE hi
    return ra | rb;
}

__global__ __launch_bounds__(256, 3)
void fusion_gemm(const float* __restrict__ W1,
                 const float* __restrict__ text_x,
                 const float* __restrict__ audio_x,
                 const float* __restrict__ video_x,
                 float* __restrict__ h1pre)   // [96][64], pre-zeroed
{
    __shared__ __align__(16) short Wbf[2][NP1 * RSTR];   // 2 x 20.2 KB
    __shared__ float biasF[2][NP1];                      // W[j][0] fp32

    const int tid = threadIdx.x;
    const int o   = blockIdx.x >> 3;
    const int c   = blockIdx.x & 7;
    const int ilo = (c * 97) >> 3;            // contiguous i-chunks of 12..13
    const int ihi = ((c + 1) * 97) >> 3;

    const int lane = tid & 63;
    const int wave = tid >> 6;
    const int quad = lane >> 4;
    const int col  = lane & 15;
    const int b    = wave * 16 + col;         // this lane's batch element

    // ---- hoisted: video B-fragments (K=96 = 3 k-steps of 32) ----
    // B-frag layout: lane holds B[k = quad*8+e][n = lane&15]
    bf16x8 bfrag[3];
#pragma unroll
    for (int ks = 0; ks < 3; ++ks) {
        const float* vp = video_x + b * HID + ks * 32 + quad * 8;
        union { bf16x8 v; uint32_t d[4]; } u;
        u.d[0] = pack2bf(vp[0], vp[1]);
        u.d[1] = pack2bf(vp[2], vp[3]);
        u.d[2] = pack2bf(vp[4], vp[5]);
        u.d[3] = pack2bf(vp[6], vp[7]);
        bfrag[ks] = u.v;
    }

    // ---- hoisted: audio epilogue weights for this lane's 28 j-slots ----
    // D layout: col = lane&15 -> b, row = quad*4 + reg -> j (verified R1)
    float aval[28];
#pragma unroll
    for (int mt = 0; mt < 7; ++mt)
#pragma unroll
        for (int r = 0; r < 4; ++r) {
            int j = mt * 16 + quad * 4 + r;
            aval[mt * 4 + r] = (j == 0) ? 1.f
                             : (j <= 96 ? audio_x[b * HID + (j - 1)] : 0.f);
        }

    // ---- staging helper: tile (o,ii) -> buffer pbuf, fp32->bf16 on the fly ----
    auto stage = [&](int ii, int pbuf) {
        const float* Wt = W1 + (long)(o * 97 + ii) * ROWLEN;
        for (int j = tid; j < NP1; j += 256) biasF[pbuf][j] = Wt[j * NP1];
        for (int w = tid; w < NP1 * 12; w += 256) {
            int j = w / 12;
            int s = w - j * 12;
            const float* p = Wt + j * NP1 + 1 + s * 8;   // union contiguous
            uint4 q;
            q.x = pack2bf(p[0], p[1]);
            q.y = pack2bf(p[2], p[3]);
            q.z = pack2bf(p[4], p[5]);
            q.w = pack2bf(p[6], p[7]);
            *reinterpret_cast<uint4*>(&Wbf[pbuf][j * RSTR + s * 8]) = q;  // 16B-aligned
        }
    };

    float sacc = 0.f;

    stage(ilo, 0);
    __syncthreads();

    for (int ii = ilo; ii < ihi; ++ii) {
        const int pb = (ii - ilo) & 1;
        if (ii + 1 < ihi) stage(ii + 1, pb ^ 1);   // overlaps compute below

        // ---- MFMA: U[j,b] = sum_k W[j,1+k]*video[b,k]; 7 m-tiles of 16 j ----
        f32x4 acc[7];
#pragma unroll
        for (int mt = 0; mt < 7; ++mt) acc[mt] = (f32x4){0.f, 0.f, 0.f, 0.f};
#pragma unroll
        for (int ks = 0; ks < 3; ++ks)
#pragma unroll
            for (int mt = 0; mt < 7; ++mt) {
                int j  = mt * 16 + col;            // A-frag row m
                int je = j > 96 ? 96 : j;          // clamp; garbage rows x0 below
                bf16x8 af = *reinterpret_cast<const bf16x8*>(
                    &Wbf[pb][je * RSTR + ks * 32 + quad * 8]);   // one ds_read_b128
                acc[mt] = __builtin_amdgcn_mfma_f32_16x16x32_bf16(af, bfrag[ks], acc[mt], 0, 0, 0);
            }

        // ---- epilogue: S[b] = sum_j aval_j * (U[j,b] + W[j,0]) ----
        float s = 0.f;
#pragma unroll
        for (int mt = 0; mt < 7; ++mt)
#pragma unroll
            for (int r = 0; r < 4; ++r) {
                int j  = mt * 16 + quad * 4 + r;
                int je = j > 96 ? 96 : j;
                s += (acc[mt][r] + biasF[pb][je]) * aval[mt * 4 + r];
            }
        s += __shfl_xor(s, 16);
        s += __shfl_xor(s, 32);                    // all quads: full sum over j

        float tw = (ii == 0) ? 1.f : text_x[b * HID + (ii - 1)];
        sacc += s * tw;                            // i-fold in register

        __syncthreads();                           // buf pb free for stage(ii+2)
    }

    if (quad == 0) atomicAdd(&h1pre[o * BATCH + b], sacc);   // 8 adds/address
}

__global__ __launch_bounds__(64)
void mlp_tail(const float* __restrict__ h1pre, const float* __restrict__ b1,
              const float* __restrict__ W2, const float* __restrict__ b2,
              const float* __restrict__ W3, const float* __restrict__ b3,
              float* __restrict__ out)
{
    __shared__ float h1s[96];
    __shared__ float h2s[48];
    const int b = blockIdx.x;
    const int t = threadIdx.x;
    for (int o = t; o < 96; o += 64) {
        float v = h1pre[o * BATCH + b] + b1[o];
        h1s[o] = v > 0.f ? v : 0.f;
    }
    __syncthreads();
    if (t < 48) {
        float acc = b2[t];
#pragma unroll 8
        for (int o = 0; o < 96; ++o) acc += W2[t * 96 + o] * h1s[o];
        h2s[t] = acc > 0.f ? acc : 0.f;
    }
    __syncthreads();
    if (t < 3) {
        float acc = b3[t];
#pragma unroll
        for (int c = 0; c < 48; ++c) acc += W3[t * 48 + c] * h2s[c];
        out[b * 3 + t] = acc;
    }
}

extern "C" void kernel_launch(void* const* d_in, const int* in_sizes, int n_in,
                              void* d_out, int out_size, void* d_ws, size_t ws_size,
                              hipStream_t stream)
{
    const float* text  = (const float*)d_in[0];
    const float* audio = (const float*)d_in[1];
    const float* video = (const float*)d_in[2];
    const float* W1    = (const float*)d_in[3];
    const float* b1    = (const float*)d_in[4];
    const float* W2    = (const float*)d_in[5];
    const float* b2    = (const float*)d_in[6];
    const float* W3    = (const float*)d_in[7];
    const float* b3    = (const float*)d_in[8];
    float* h1pre = (float*)d_ws;                       // 96*64 fp32

    hipMemsetAsync(h1pre, 0, HID * BATCH * sizeof(float), stream);
    fusion_gemm<<<96 * 8, 256, 0, stream>>>(W1, text, audio, video, h1pre);
    mlp_tail<<<BATCH, 64, 0, stream>>>(h1pre, b1, W2, b2, W3, b3, (float*)d_out);
}